// Round 5
// baseline (261.713 us; speedup 1.0000x reference)
//
#include <hip/hip_runtime.h>

// EmbeddingDropout: out[b,s,:] = weight[words[b,s], :] * mask[words[b,s]]
// words: (8,2048) int32; weight: (50257,768) fp32; mask: (50257,1) fp32
// out: (8,2048,768) fp32 = 3,145,728 float4 elements.
//
// R1-R4 lessons: three structurally different kernels (MLP=1 / MLP=8 /
// MLP=12+nt) all measure 208-215 µs -> dur_us is dominated by fixed
// per-iteration harness traffic (ws/out poison + input restore + ~18 small
// reset dispatches). Kernel's own duration unresolved: 15-60 µs.
//
// R5 PROBE: launch the identical kernel 4x (idempotent). dur - 208 = 3*K_warm,
// isolating the kernel's structural cost with L3-warm reads. K_warm ~12 µs
// => kernel at floor (declare roofline); K_warm ~60 µs => real headroom.

#define DIM 768
#define V4_PER_ROW (DIM / 4)   // 192 float4 per row
#define ELEMS 12
#define BLOCK 256

typedef float f4 __attribute__((ext_vector_type(4)));

__global__ __launch_bounds__(BLOCK) void embed_dropout_kernel(
    const int* __restrict__ words,
    const float* __restrict__ weight,
    const float* __restrict__ mask,
    f4* __restrict__ out) {
    const unsigned int base =
        blockIdx.x * (BLOCK * ELEMS) + threadIdx.x;

    int idx[ELEMS];
    unsigned int r[ELEMS];

    // Stage 1: all token-index loads issued back-to-back (independent).
    #pragma unroll
    for (int k = 0; k < ELEMS; ++k) {
        const unsigned int i = base + (unsigned int)k * BLOCK;
        const unsigned int tok = i / V4_PER_ROW;   // magic-mul
        r[k] = i - tok * V4_PER_ROW;
        idx[k] = words[tok];
    }

    // Stage 2: all mask + weight loads issued (12 independent chains).
    float scale[ELEMS];
    f4 v[ELEMS];
    #pragma unroll
    for (int k = 0; k < ELEMS; ++k) {
        scale[k] = mask[idx[k]];
        const f4* wrow = (const f4*)(weight + (size_t)idx[k] * DIM) + r[k];
        v[k] = __builtin_nontemporal_load(wrow);
    }

    // Stage 3: scale + streaming store (output never re-read by us).
    #pragma unroll
    for (int k = 0; k < ELEMS; ++k) {
        f4 o = v[k] * scale[k];
        __builtin_nontemporal_store(o, &out[base + (unsigned int)k * BLOCK]);
    }
}

extern "C" void kernel_launch(void* const* d_in, const int* in_sizes, int n_in,
                              void* d_out, int out_size, void* d_ws, size_t ws_size,
                              hipStream_t stream) {
    const int* words = (const int*)d_in[0];       // (8,2048) int32
    const float* weight = (const float*)d_in[1];  // (50257,768) fp32
    const float* mask = (const float*)d_in[2];    // (50257,1) fp32
    f4* out = (f4*)d_out;                         // (8,2048,768) fp32

    const unsigned int total4 = (unsigned int)(out_size / 4);        // 3,145,728
    const unsigned int per_block = BLOCK * ELEMS;                    // 3072
    const unsigned int grid = (total4 + per_block - 1) / per_block;  // 1024 exact

    // PROBE: 4 identical launches. Same work every call (idempotent).
    // dur_us - single-launch baseline (208) ~= 3 * K_warm.
    for (int rep = 0; rep < 4; ++rep) {
        embed_dropout_kernel<<<grid, BLOCK, 0, stream>>>(words, weight, mask, out);
    }
}